// Round 6
// baseline (198.459 us; speedup 1.0000x reference)
//
#include <hip/hip_runtime.h>
#include <stdint.h>

#define N_TOK  16384
#define EMB    512
#define NEMB   2048
#define NCHUNK 32            // 64 templates per chunk
#define CWIN   2.5e-4f       // ref-f32-grid + bf16 score-noise margin (passed R5-R7)
#define WCAP   524288

typedef __attribute__((ext_vector_type(8))) short s16x8;
typedef __attribute__((ext_vector_type(4))) float f32x4;

__device__ __forceinline__ unsigned short f2bf(float f) {   // RNE f32 -> bf16
  unsigned u = __float_as_uint(f);
  u += 0x7fffu + ((u >> 16) & 1u);
  return (unsigned short)(u >> 16);
}
// monotone f32 -> u32 (total order, NaN sorts above all reals)
__device__ __forceinline__ unsigned mapf(float f) {
  unsigned u = __float_as_uint(f);
  return (u >> 31) ? ~u : (u | 0x80000000u);
}
__device__ __forceinline__ float unmapf(unsigned u) {
  return __uint_as_float((u >> 31) ? (u & 0x7fffffffu) : ~u);
}

// numpy pairwise_sum emulation for sum(x*x) over 512 contiguous f32.
__device__ __forceinline__ float pairwise512_sq(const float* se, int lane) {
  int l = lane & 31;
  int b = l >> 3, j = l & 7;
  const float* base = se + b * 128 + j;
  float x = base[0];
  float r = __fmul_rn(x, x);
#pragma unroll
  for (int k = 1; k < 16; ++k) {
    float y = base[8 * k];
    r = __fadd_rn(r, __fmul_rn(y, y));
  }
  r = __fadd_rn(r, __shfl_xor(r, 1));
  r = __fadd_rn(r, __shfl_xor(r, 2));
  r = __fadd_rn(r, __shfl_xor(r, 4));
  r = __fadd_rn(r, __shfl_xor(r, 8));
  r = __fadd_rn(r, __shfl_xor(r, 16));
  return r;
}

// ---------- kernel 1: fused prep; bf16 copies stored PANEL-MAJOR ----------
// Panel-major: [rowblk = row/128][kt = col/32][128 rows][32 cols] bf16, i.e.
// each 8 KB K-panel contiguous. Score's global_load_lds streams whole panels
// densely (no 2x cache-line over-fetch of the old row-major LD=1KB layout).
__global__ __launch_bounds__(256) void prep_kernel(
    const float* __restrict__ tmp, const float* __restrict__ enc,
    unsigned short* __restrict__ thi, float* __restrict__ tsq,
    unsigned short* __restrict__ ehi, float* __restrict__ esq,
    int* __restrict__ wcount) {
  __shared__ float se[4][EMB];
  int wv = threadIdx.x >> 6, lane = threadIdx.x & 63;
  int row = blockIdx.x * 4 + wv;                             // 18432 rows
  if (blockIdx.x == 0 && threadIdx.x == 0) *wcount = 0;
  bool isT = row < NEMB;
  const float* src = isT ? (tmp + (size_t)row * EMB)
                         : (enc + (size_t)(row - NEMB) * EMB);
  const float4* p = (const float4*)src + lane * 2;
  float4 v0 = p[0], v1 = p[1];
  float f[8] = {v0.x, v0.y, v0.z, v0.w, v1.x, v1.y, v1.z, v1.w};
  unsigned h[8];
#pragma unroll
  for (int i = 0; i < 8; ++i) { h[i] = f2bf(f[i]); se[wv][lane * 8 + i] = f[i]; }
  uint4 packed = { h[0] | (h[1] << 16), h[2] | (h[3] << 16),
                   h[4] | (h[5] << 16), h[6] | (h[7] << 16) };
  // panel-major destination: lane covers cols lane*8..+7 = panel kt=lane>>2,
  // byte (lane&3)*16 of row's 64-B segment.
  int lrow = isT ? row : row - NEMB;
  int blk = lrow >> 7, lr = lrow & 127;
  int kt = lane >> 2, cb = (lane & 3) * 16;
  char* base = (char*)(isT ? thi : ehi);
  *(uint4*)(base + (((size_t)(blk * 16 + kt)) << 13) + lr * 64 + cb) = packed;
  __syncthreads();
  float s = pairwise512_sq(se[wv], lane);
  if (lane == 0) { if (isT) tsq[row] = s; else esq[row - NEMB] = s; }
}

// ---------- kernel 2: 128x256-tile, 4-wave, 3-deep counted-vmcnt GEMM ----------
// R5 pipeline (verified: 0 conflicts, no spill, robust TLP) with two changes:
//  - panel-major operands: every STAGE is a dense 8 KB stream -> FETCH ~halves
//    (no line over-fetch), L2-miss transactions halve.
//  - BN=256 (acc[4][8], 64x128 per wave): halves A-panel readers, doubles
//    MFMA per staged byte (better latency cover per buffer).
// LDS: A ring 3x8 KB + B ring 3x16 KB = 72 KB -> 2 blocks/CU (8 waves/CU).
// STAGE = 6 loads/thread (A:2, B:4); ledger: steady wait vmcnt(6) (panels
// t+1,t+2 in flight, need t+1), drain vmcnt(0) at t>=14. Never 0 mid-loop.
// Granule swizzle P ^= ((P>>7)&3)<<4 (16-B granules; involution; R5-verified
// 0 conflicts) applied via inverse-swizzled global source + linear
// global_load_lds dest + swizzled ds_read.
// Per-acc K order: t ascending, same 16x16x32 intrinsic -> scores
// BIT-IDENTICAL to R0..R5; downstream CWIN/refine logic unchanged.
__global__ __launch_bounds__(256, 2) void score_kernel(
    const unsigned short* __restrict__ ehi, const unsigned short* __restrict__ thi,
    const float* __restrict__ tsq,
    unsigned long long* __restrict__ keyc, unsigned* __restrict__ s2c) {
  __shared__ __align__(16) char smem[73728];       // A: 3x8 KB, B at 24576: 3x16 KB
  const int tid = threadIdx.x, w = tid >> 6, lane = tid & 63;
  const int q = lane >> 4, r = lane & 15;
  const int wr = w >> 1, wc = w & 1;               // 2M x 2N wave grid
  const int tokb = (int)blockIdx.x >> 3;           // 0..127 (128 tokens each)
  const int nbp  = (int)blockIdx.x & 7;            // 0..7   (256 templates each)

  // ---- stage-source precompute (inverse swizzle of linear dest) ----
  // A: linear dests i*4096 + tid*16, i=0..1 (8 KB panel)
  // B: linear dests i*4096 + tid*16, i=0..3 (16 KB = 2 sub-panels of 8 KB)
  const unsigned short* paA[2];
  const unsigned short* pbB[4];
#pragma unroll
  for (int i = 0; i < 2; ++i) {
    int Lp = i * 4096 + tid * 16;
    int P = Lp ^ (((Lp >> 7) & 3) << 4);
    paA[i] = (const unsigned short*)((const char*)ehi
             + (((size_t)tokb * 16) << 13) + (P >> 6) * 64 + (P & 63));
  }
#pragma unroll
  for (int i = 0; i < 4; ++i) {
    int Lp = i * 4096 + tid * 16;
    int P = Lp ^ (((Lp >> 7) & 3) << 4);
    int sub = P >> 13, rw = (P >> 6) & 127, cbyte = P & 63;
    pbB[i] = (const unsigned short*)((const char*)thi
             + (((size_t)((nbp * 2 + sub) * 16)) << 13) + rw * 64 + cbyte);
  }

#define GLD(src, dst)                                                    \
  __builtin_amdgcn_global_load_lds(                                      \
      (const __attribute__((address_space(1))) void*)(src),              \
      (__attribute__((address_space(3))) void*)(dst), 16, 0, 0)
#define STAGE(t) do {                                                    \
    char* da_ = smem + ((t) % 3) * 8192 + tid * 16;                      \
    char* db_ = smem + 24576 + ((t) % 3) * 16384 + tid * 16;             \
    GLD((const char*)paA[0] + (size_t)(t) * 8192, da_);                  \
    GLD((const char*)paA[1] + (size_t)(t) * 8192, da_ + 4096);           \
    GLD((const char*)pbB[0] + (size_t)(t) * 8192, db_);                  \
    GLD((const char*)pbB[1] + (size_t)(t) * 8192, db_ + 4096);           \
    GLD((const char*)pbB[2] + (size_t)(t) * 8192, db_ + 8192);           \
    GLD((const char*)pbB[3] + (size_t)(t) * 8192, db_ + 12288);          \
  } while (0)

  // ---- swizzled fragment-read offsets ----
  int offA[4], offB[8];
#pragma unroll
  for (int m = 0; m < 4; ++m) {
    int P = (wr * 64 + m * 16 + r) * 64 + q * 16;
    offA[m] = P ^ (((P >> 7) & 3) << 4);
  }
#pragma unroll
  for (int n = 0; n < 8; ++n) {
    int P = (wc * 128 + n * 16 + r) * 64 + q * 16;
    offB[n] = P ^ (((P >> 7) & 3) << 4);
  }

  f32x4 acc[4][8];
#pragma unroll
  for (int m = 0; m < 4; ++m)
#pragma unroll
    for (int n = 0; n < 8; ++n) acc[m][n] = (f32x4){0.f, 0.f, 0.f, 0.f};

  // ---- prologue: panels 0,1 in flight (12 units); need panel 0 -> vmcnt(6)
  STAGE(0); STAGE(1);
  asm volatile("s_waitcnt vmcnt(6)" ::: "memory");
  __builtin_amdgcn_s_barrier();

#pragma unroll
  for (int t = 0; t < 16; ++t) {
    const char* Ab_ = smem + (t % 3) * 8192;
    const char* Bb_ = smem + 24576 + (t % 3) * 16384;
    if (t + 2 < 16) STAGE(t + 2);                  // targets buf[(t-1)%3]: WAR-safe
    s16x8 af[4], bf[8];
#pragma unroll
    for (int m = 0; m < 4; ++m) af[m] = *(const s16x8*)(Ab_ + offA[m]);
#pragma unroll
    for (int n = 0; n < 8; ++n) bf[n] = *(const s16x8*)(Bb_ + offB[n]);
    __builtin_amdgcn_s_setprio(1);
#pragma unroll
    for (int n = 0; n < 8; ++n) {
      acc[0][n] = __builtin_amdgcn_mfma_f32_16x16x32_bf16(af[0], bf[n], acc[0][n], 0, 0, 0);
      acc[1][n] = __builtin_amdgcn_mfma_f32_16x16x32_bf16(af[1], bf[n], acc[1][n], 0, 0, 0);
      acc[2][n] = __builtin_amdgcn_mfma_f32_16x16x32_bf16(af[2], bf[n], acc[2][n], 0, 0, 0);
      acc[3][n] = __builtin_amdgcn_mfma_f32_16x16x32_bf16(af[3], bf[n], acc[3][n], 0, 0, 0);
    }
    __builtin_amdgcn_s_setprio(0);
    // panels t+1 (needed next) and t+2 outstanding -> allow 6; drain at tail
    if (t < 14) { asm volatile("s_waitcnt vmcnt(6)" ::: "memory"); }
    else        { asm volatile("s_waitcnt vmcnt(0)" ::: "memory"); }
    __builtin_amdgcn_s_barrier();
  }

  // ---- epilogue: in-register argmin; wave (wr,wc) owns tokens
  // tokb*128 + wr*64..+63 of chunks nbp*4 + wc*2 + {0,1}. Fold n, butterfly r.
#pragma unroll
  for (int nh = 0; nh < 2; ++nh) {
    const int chunk = nbp * 4 + wc * 2 + nh;
    const int nbase = chunk * 64;
    float tq[4];
#pragma unroll
    for (int nn = 0; nn < 4; ++nn) tq[nn] = tsq[nbase + nn * 16 + r];
#pragma unroll
    for (int m = 0; m < 4; ++m) {
#pragma unroll
      for (int i = 0; i < 4; ++i) {
        unsigned long long k1 = ~0ULL; unsigned s2m = 0xffffffffu;
#pragma unroll
        for (int nn = 0; nn < 4; ++nn) {            // nn ascending = template ascending
          float s = tq[nn] - 2.0f * acc[m][nh * 4 + nn][i];
          unsigned sm = mapf(s);
          unsigned long long k =
              ((unsigned long long)sm << 32) | (unsigned)(nbase + nn * 16 + r);
          if (k < k1) { unsigned o = (unsigned)(k1 >> 32); s2m = o < s2m ? o : s2m; k1 = k; }
          else s2m = sm < s2m ? sm : s2m;
        }
#pragma unroll
        for (int mask = 1; mask < 16; mask <<= 1) {
          unsigned long long ok = __shfl_xor(k1, mask);
          unsigned os = __shfl_xor(s2m, mask);
          if (ok < k1) { unsigned o = (unsigned)(k1 >> 32); s2m = o < s2m ? o : s2m; k1 = ok; }
          else { unsigned o = (unsigned)(ok >> 32); s2m = o < s2m ? o : s2m; }
          s2m = os < s2m ? os : s2m;
        }
        if (r == 0) {
          int token = tokb * 128 + wr * 64 + m * 16 + q * 4 + i;
          keyc[(size_t)chunk * N_TOK + token] = k1;
          s2c [(size_t)chunk * N_TOK + token] = s2m;
        }
      }
    }
  }
#undef GLD
#undef STAGE
}

// ---------- kernel 3: 32-way key merge, flag, worklist; inits rkey ----------
__global__ __launch_bounds__(256) void merge_kernel(
    const unsigned long long* __restrict__ keyc, const unsigned* __restrict__ s2c,
    int* __restrict__ bestIdx, int* __restrict__ flag, int* __restrict__ work,
    int* __restrict__ wcount, unsigned long long* __restrict__ rkey) {
  int t = blockIdx.x * 256 + threadIdx.x;
  if (t >= N_TOK) return;
  rkey[t] = ~0ULL;
  unsigned long long K = ~0ULL; unsigned S = 0xffffffffu;
  for (int c = 0; c < NCHUNK; ++c) {
    unsigned long long k = keyc[(size_t)c * N_TOK + t];
    unsigned s2 = s2c[(size_t)c * N_TOK + t];
    if (k < K) { unsigned o = (unsigned)(K >> 32); S = o < S ? o : S; K = k; }
    else { unsigned o = (unsigned)(k >> 32); S = o < S ? o : S; }
    S = s2 < S ? s2 : S;
  }
  float best_f   = unmapf((unsigned)(K >> 32));
  float second_f = unmapf(S);
  int idx = (int)(unsigned)(K & 0xffffffffu);
  bestIdx[t] = idx;
  bool ok = (second_f - best_f >= CWIN) && (idx >= 0) && (idx < NEMB) && (best_f == best_f);
  flag[t] = ok ? 0 : 1;
  if (!ok) {
    bool nanCase = !(best_f == best_f);
    float limit = best_f + CWIN;
    for (int c = 0; c < NCHUNK; ++c) {
      float cf = unmapf((unsigned)(keyc[(size_t)c * N_TOK + t] >> 32));
      if (nanCase || !(cf > limit)) {               // NaN-safe candidate test
        int pos = atomicAdd(wcount, 1);
        if (pos < WCAP) work[pos] = t * NCHUNK + c;
      }
    }
  }
}

// ---------- kernel 4: f32-emulated rescan, 16 lanes per template ----------
// 4 templates per wave in parallel (group g = lane>>4); double accumulation is
// associativity-equivalent to the previous 64-lane tree (rounds once to f32).
__global__ __launch_bounds__(256) void refine_kernel(
    const float* __restrict__ enc, const float* __restrict__ tmp,
    const float* __restrict__ esq, const float* __restrict__ tsq,
    const int* __restrict__ work, const int* __restrict__ wcount,
    unsigned long long* __restrict__ rkey) {
  int total = *wcount; if (total > WCAP) total = WCAP;
  __shared__ float se[EMB];
  const int wv = threadIdx.x >> 6, lane = threadIdx.x & 63;
  const int g = lane >> 4, l16 = lane & 15;
  for (int p = blockIdx.x; p < total; p += gridDim.x) {
    __syncthreads();
    int item = work[p];
    int token = item / NCHUNK, c = item % NCHUNK;
    const float4* erow = (const float4*)(enc + (size_t)token * EMB);
    for (int i = threadIdx.x; i < 128; i += 256) ((float4*)se)[i] = erow[i];
    __syncthreads();
    float e2 = esq[token];
    unsigned long long lkey = ~0ULL;
#pragma unroll
    for (int j = 0; j < 4; ++j) {
      int m = c * 64 + wv * 16 + j * 4 + g;
      const float4* trow = (const float4*)(tmp + (size_t)m * EMB);
      double s = 0.0;
#pragma unroll
      for (int k = 0; k < 8; ++k) {
        float4 a = trow[l16 + 16 * k];
        float4 b = ((const float4*)se)[l16 + 16 * k];
        s += (double)a.x * b.x + (double)a.y * b.y
           + (double)a.z * b.z + (double)a.w * b.w;
      }
      s += __shfl_xor(s, 1); s += __shfl_xor(s, 2);
      s += __shfl_xor(s, 4); s += __shfl_xor(s, 8);
      if (l16 == 0) {
        float M  = (float)s;
        float d1 = __fadd_rn(e2, -__fmul_rn(2.0f, M));
        float d2 = __fadd_rn(d1, tsq[m]);            // full dist >= 0: bits monotone
        unsigned long long key =
            ((unsigned long long)__float_as_uint(d2) << 32) | (unsigned)m;
        if (key < lkey) lkey = key;
      }
    }
    if (l16 == 0 && lkey != ~0ULL) atomicMin(&rkey[token], lkey);
  }
}

// ---------- kernel 5: gather f32 rows + zidx as f32 ----------
__global__ void gather_kernel(const float* __restrict__ tmp, const int* __restrict__ bestIdx,
                              const int* __restrict__ flag,
                              const unsigned long long* __restrict__ rkey,
                              float* __restrict__ out) {
  int token = blockIdx.x * 4 + (threadIdx.x >> 6);
  int lane = threadIdx.x & 63;
  int idx = flag[token] ? (int)(unsigned)(rkey[token] & 0xffffffffULL) : bestIdx[token];
  idx = idx < 0 ? 0 : (idx > NEMB - 1 ? NEMB - 1 : idx);
  const float4* src = (const float4*)(tmp + (size_t)idx * EMB) + lane * 2;
  float4* dst = (float4*)(out + (size_t)token * EMB) + lane * 2;
  dst[0] = src[0];
  dst[1] = src[1];
  if (lane == 0) out[(size_t)N_TOK * EMB + token] = (float)idx;
}

extern "C" void kernel_launch(void* const* d_in, const int* in_sizes, int n_in,
                              void* d_out, int out_size, void* d_ws, size_t ws_size,
                              hipStream_t stream) {
  const float* enc = (const float*)d_in[0];
  const float* tmp = (const float*)d_in[1];
  float* out = (float*)d_out;
  char* ws = (char*)d_ws;
  unsigned short* thi = (unsigned short*)ws;                 //  2,097,152 B (panel-major)
  unsigned short* ehi = (unsigned short*)(ws + 2097152);     // 16,777,216 B (panel-major)
  float* tsq      = (float*)(ws + 18874368);                 //      8,192 B
  float* esq      = (float*)(ws + 18882560);                 //     65,536 B
  unsigned long long* keyc = (unsigned long long*)(ws + 18948096); // 4,194,304 B
  unsigned* s2c   = (unsigned*)(ws + 23142400);              //  2,097,152 B
  int*   bestIdx  = (int*)  (ws + 25239552);                 //     65,536 B
  int*   flag     = (int*)  (ws + 25305088);                 //     65,536 B
  unsigned long long* rkey = (unsigned long long*)(ws + 25370624); // 131,072 B
  int*   wcount   = (int*)  (ws + 25501696);                 //         64 B
  int*   work     = (int*)  (ws + 25501760);                 //  2,097,152 B

  prep_kernel  <<<4608,      256, 0, stream>>>(tmp, enc, thi, tsq, ehi, esq, wcount);
  score_kernel <<<1024,      256, 0, stream>>>(ehi, thi, tsq, keyc, s2c);
  merge_kernel <<<N_TOK/256, 256, 0, stream>>>(keyc, s2c, bestIdx, flag, work, wcount, rkey);
  refine_kernel<<<1024,      256, 0, stream>>>(enc, tmp, esq, tsq, work, wcount, rkey);
  gather_kernel<<<N_TOK/4,   256, 0, stream>>>(tmp, bestIdx, flag, rkey, out);
}

// Round 7
// 184.147 us; speedup vs baseline: 1.0777x; 1.0777x over previous
//
#include <hip/hip_runtime.h>
#include <stdint.h>

#define N_TOK  16384
#define EMB    512
#define NEMB   2048
#define NCHUNK 32            // 64 templates per chunk
#define CWIN   2.5e-4f       // ref-f32-grid + bf16 score-noise margin (passed R5-R7)
#define WCAP   524288

typedef __attribute__((ext_vector_type(8))) short s16x8;
typedef __attribute__((ext_vector_type(4))) float f32x4;

__device__ __forceinline__ unsigned short f2bf(float f) {   // RNE f32 -> bf16
  unsigned u = __float_as_uint(f);
  u += 0x7fffu + ((u >> 16) & 1u);
  return (unsigned short)(u >> 16);
}
// monotone f32 -> u32 (total order, NaN sorts above all reals)
__device__ __forceinline__ unsigned mapf(float f) {
  unsigned u = __float_as_uint(f);
  return (u >> 31) ? ~u : (u | 0x80000000u);
}
__device__ __forceinline__ float unmapf(unsigned u) {
  return __uint_as_float((u >> 31) ? (u & 0x7fffffffu) : ~u);
}

// DPP helpers: permute within 16-lane rows (all lanes active, bound_ctrl=1).
// quad_perm xor1 = 0xB1, xor2 = 0x4E; row_ror:4 = 0x124, row_ror:8 = 0x128.
// Math field-validated in R2 (passed absmax 0); R2's regression was register
// spill from its persistent-loop structure, not this reduction.
template<int CTRL>
__device__ __forceinline__ float dppf(float x) {
  return __uint_as_float((unsigned)__builtin_amdgcn_update_dpp(
      0, (int)__float_as_uint(x), CTRL, 0xF, 0xF, true));
}
template<int CTRL>
__device__ __forceinline__ unsigned dppu(unsigned x) {
  return (unsigned)__builtin_amdgcn_update_dpp(0, (int)x, CTRL, 0xF, 0xF, true);
}

// numpy pairwise_sum emulation for sum(x*x) over 512 contiguous f32.
__device__ __forceinline__ float pairwise512_sq(const float* se, int lane) {
  int l = lane & 31;
  int b = l >> 3, j = l & 7;
  const float* base = se + b * 128 + j;
  float x = base[0];
  float r = __fmul_rn(x, x);
#pragma unroll
  for (int k = 1; k < 16; ++k) {
    float y = base[8 * k];
    r = __fadd_rn(r, __fmul_rn(y, y));
  }
  r = __fadd_rn(r, __shfl_xor(r, 1));
  r = __fadd_rn(r, __shfl_xor(r, 2));
  r = __fadd_rn(r, __shfl_xor(r, 4));
  r = __fadd_rn(r, __shfl_xor(r, 8));
  r = __fadd_rn(r, __shfl_xor(r, 16));
  return r;
}

// ---------- kernel 1: fused prep; bf16 copies stored PANEL-MAJOR ----------
// Panel-major: [rowblk = row/128][kt = col/32][128 rows][32 cols] bf16, i.e.
// each 8 KB K-panel contiguous -> score's global_load_lds streams densely.
__global__ __launch_bounds__(256) void prep_kernel(
    const float* __restrict__ tmp, const float* __restrict__ enc,
    unsigned short* __restrict__ thi, float* __restrict__ tsq,
    unsigned short* __restrict__ ehi, float* __restrict__ esq,
    int* __restrict__ wcount) {
  __shared__ float se[4][EMB];
  int wv = threadIdx.x >> 6, lane = threadIdx.x & 63;
  int row = blockIdx.x * 4 + wv;                             // 18432 rows
  if (blockIdx.x == 0 && threadIdx.x == 0) *wcount = 0;
  bool isT = row < NEMB;
  const float* src = isT ? (tmp + (size_t)row * EMB)
                         : (enc + (size_t)(row - NEMB) * EMB);
  const float4* p = (const float4*)src + lane * 2;
  float4 v0 = p[0], v1 = p[1];
  float f[8] = {v0.x, v0.y, v0.z, v0.w, v1.x, v1.y, v1.z, v1.w};
  unsigned h[8];
#pragma unroll
  for (int i = 0; i < 8; ++i) { h[i] = f2bf(f[i]); se[wv][lane * 8 + i] = f[i]; }
  uint4 packed = { h[0] | (h[1] << 16), h[2] | (h[3] << 16),
                   h[4] | (h[5] << 16), h[6] | (h[7] << 16) };
  int lrow = isT ? row : row - NEMB;
  int blk = lrow >> 7, lr = lrow & 127;
  int kt = lane >> 2, cb = (lane & 3) * 16;
  char* base = (char*)(isT ? thi : ehi);
  *(uint4*)(base + (((size_t)(blk * 16 + kt)) << 13) + lr * 64 + cb) = packed;
  __syncthreads();
  float s = pairwise512_sq(se[wv], lane);
  if (lane == 0) { if (isT) tsq[row] = s; else esq[row - NEMB] = s; }
}

// ---------- kernel 2: 128x256-tile, 4-wave, 3-deep counted-vmcnt GEMM ----------
// K-loop frozen from R6 (56 us; 0 conflicts, no spill; structural wall per
// R1/R5/R6 triangulation: staged-bytes x service-BW tradeoff is register-file
// capped at ~56 us for every reachable tile/occupancy corner).
// ONLY change vs R6: DPP float-pair argmin epilogue (R2-validated math)
// replaces the 64-bit shuffle butterfly: ~3x fewer VALU ops, no LDS-pipe ops.
// Exact-tie key differences route to refine (margin < CWIN) -> outputs equal.
__global__ __launch_bounds__(256, 2) void score_kernel(
    const unsigned short* __restrict__ ehi, const unsigned short* __restrict__ thi,
    const float* __restrict__ tsq,
    unsigned long long* __restrict__ keyc, unsigned* __restrict__ s2c) {
  __shared__ __align__(16) char smem[73728];       // A: 3x8 KB, B at 24576: 3x16 KB
  const int tid = threadIdx.x, w = tid >> 6, lane = tid & 63;
  const int q = lane >> 4, r = lane & 15;
  const int wr = w >> 1, wc = w & 1;               // 2M x 2N wave grid
  const int tokb = (int)blockIdx.x >> 3;           // 0..127 (128 tokens each)
  const int nbp  = (int)blockIdx.x & 7;            // 0..7   (256 templates each)

  // ---- stage-source precompute (inverse swizzle of linear dest) ----
  const unsigned short* paA[2];
  const unsigned short* pbB[4];
#pragma unroll
  for (int i = 0; i < 2; ++i) {
    int Lp = i * 4096 + tid * 16;
    int P = Lp ^ (((Lp >> 7) & 3) << 4);
    paA[i] = (const unsigned short*)((const char*)ehi
             + (((size_t)tokb * 16) << 13) + (P >> 6) * 64 + (P & 63));
  }
#pragma unroll
  for (int i = 0; i < 4; ++i) {
    int Lp = i * 4096 + tid * 16;
    int P = Lp ^ (((Lp >> 7) & 3) << 4);
    int sub = P >> 13, rw = (P >> 6) & 127, cbyte = P & 63;
    pbB[i] = (const unsigned short*)((const char*)thi
             + (((size_t)((nbp * 2 + sub) * 16)) << 13) + rw * 64 + cbyte);
  }

#define GLD(src, dst)                                                    \
  __builtin_amdgcn_global_load_lds(                                      \
      (const __attribute__((address_space(1))) void*)(src),              \
      (__attribute__((address_space(3))) void*)(dst), 16, 0, 0)
#define STAGE(t) do {                                                    \
    char* da_ = smem + ((t) % 3) * 8192 + tid * 16;                      \
    char* db_ = smem + 24576 + ((t) % 3) * 16384 + tid * 16;             \
    GLD((const char*)paA[0] + (size_t)(t) * 8192, da_);                  \
    GLD((const char*)paA[1] + (size_t)(t) * 8192, da_ + 4096);           \
    GLD((const char*)pbB[0] + (size_t)(t) * 8192, db_);                  \
    GLD((const char*)pbB[1] + (size_t)(t) * 8192, db_ + 4096);           \
    GLD((const char*)pbB[2] + (size_t)(t) * 8192, db_ + 8192);           \
    GLD((const char*)pbB[3] + (size_t)(t) * 8192, db_ + 12288);          \
  } while (0)

  // ---- swizzled fragment-read offsets ----
  int offA[4], offB[8];
#pragma unroll
  for (int m = 0; m < 4; ++m) {
    int P = (wr * 64 + m * 16 + r) * 64 + q * 16;
    offA[m] = P ^ (((P >> 7) & 3) << 4);
  }
#pragma unroll
  for (int n = 0; n < 8; ++n) {
    int P = (wc * 128 + n * 16 + r) * 64 + q * 16;
    offB[n] = P ^ (((P >> 7) & 3) << 4);
  }

  f32x4 acc[4][8];
#pragma unroll
  for (int m = 0; m < 4; ++m)
#pragma unroll
    for (int n = 0; n < 8; ++n) acc[m][n] = (f32x4){0.f, 0.f, 0.f, 0.f};

  // ---- prologue: panels 0,1 in flight (12 units); need panel 0 -> vmcnt(6)
  STAGE(0); STAGE(1);
  asm volatile("s_waitcnt vmcnt(6)" ::: "memory");
  __builtin_amdgcn_s_barrier();

#pragma unroll
  for (int t = 0; t < 16; ++t) {
    const char* Ab_ = smem + (t % 3) * 8192;
    const char* Bb_ = smem + 24576 + (t % 3) * 16384;
    if (t + 2 < 16) STAGE(t + 2);                  // targets buf[(t-1)%3]: WAR-safe
    s16x8 af[4], bf[8];
#pragma unroll
    for (int m = 0; m < 4; ++m) af[m] = *(const s16x8*)(Ab_ + offA[m]);
#pragma unroll
    for (int n = 0; n < 8; ++n) bf[n] = *(const s16x8*)(Bb_ + offB[n]);
    __builtin_amdgcn_s_setprio(1);
#pragma unroll
    for (int n = 0; n < 8; ++n) {
      acc[0][n] = __builtin_amdgcn_mfma_f32_16x16x32_bf16(af[0], bf[n], acc[0][n], 0, 0, 0);
      acc[1][n] = __builtin_amdgcn_mfma_f32_16x16x32_bf16(af[1], bf[n], acc[1][n], 0, 0, 0);
      acc[2][n] = __builtin_amdgcn_mfma_f32_16x16x32_bf16(af[2], bf[n], acc[2][n], 0, 0, 0);
      acc[3][n] = __builtin_amdgcn_mfma_f32_16x16x32_bf16(af[3], bf[n], acc[3][n], 0, 0, 0);
    }
    __builtin_amdgcn_s_setprio(0);
    if (t < 14) { asm volatile("s_waitcnt vmcnt(6)" ::: "memory"); }
    else        { asm volatile("s_waitcnt vmcnt(0)" ::: "memory"); }
    __builtin_amdgcn_s_barrier();
  }

  // ---- epilogue: DPP float-pair argmin (R2-validated). Wave (wr,wc) owns
  // tokens tokb*128 + wr*64..+63 of chunks nbp*4 + wc*2 + {0,1}.
#define FOLD(CTRL) { float os_ = dppf<CTRL>(sb), os2_ = dppf<CTRL>(s2f);        \
    float mx_ = fmaxf(sb, os_);                                                 \
    s2f = fminf(fminf(s2f, os2_), mx_); sb = fminf(sb, os_); }
#define FOLDL(CTRL) { unsigned ol_ = dppu<CTRL>(li); li = li < ol_ ? li : ol_; }
#pragma unroll
  for (int nh = 0; nh < 2; ++nh) {
    const int chunk = nbp * 4 + wc * 2 + nh;
    const int nbase = chunk * 64;
    const float tq0 = tsq[nbase + r], tq1 = tsq[nbase + 16 + r],
                tq2 = tsq[nbase + 32 + r], tq3 = tsq[nbase + 48 + r];
#pragma unroll
    for (int m = 0; m < 4; ++m) {
      unsigned long long kk[4]; unsigned ss[4];
#pragma unroll
      for (int i = 0; i < 4; ++i) {
        float s0 = fmaf(-2.f, acc[m][nh * 4 + 0][i], tq0);  // == tq - fl(2*acc)
        float s1 = fmaf(-2.f, acc[m][nh * 4 + 1][i], tq1);
        float s2v = fmaf(-2.f, acc[m][nh * 4 + 2][i], tq2);
        float s3 = fmaf(-2.f, acc[m][nh * 4 + 3][i], tq3);
        // within-lane min + exact second-of-4 (dup-safe)
        float n01 = fminf(s0, s1), X01 = fmaxf(s0, s1);
        float n23 = fminf(s2v, s3), X23 = fmaxf(s2v, s3);
        float sb = fminf(n01, n23);
        float s2f = fminf(fminf(X01, X23), fmaxf(n01, n23));
        // row fold: (min, second) pair-merge, cyclic so all lanes get result
        FOLD(0xB1) FOLD(0x4E) FOLD(0x124) FOLD(0x128)
        // exact lexicographic index recovery: lowest (n,r) matching row-min
        unsigned li = 0xFFFFFFFFu;
        li = (s3  == sb) ? (unsigned)(48 + r) : li;
        li = (s2v == sb) ? (unsigned)(32 + r) : li;
        li = (s1  == sb) ? (unsigned)(16 + r) : li;
        li = (s0  == sb) ? (unsigned)(r)      : li;
        FOLDL(0xB1) FOLDL(0x4E) FOLDL(0x124) FOLDL(0x128)
        kk[i] = ((unsigned long long)mapf(sb) << 32) | (unsigned)(nbase + (int)li);
        ss[i] = mapf(s2f);
      }
      if (r == 0) {
        size_t base = (size_t)chunk * N_TOK +
                      (size_t)(tokb * 128 + wr * 64 + m * 16 + q * 4);
        ((ulonglong2*)&keyc[base])[0] = make_ulonglong2(kk[0], kk[1]);
        ((ulonglong2*)&keyc[base])[1] = make_ulonglong2(kk[2], kk[3]);
        *(uint4*)&s2c[base] = make_uint4(ss[0], ss[1], ss[2], ss[3]);
      }
    }
  }
#undef FOLD
#undef FOLDL
#undef GLD
#undef STAGE
}

// ---------- kernel 3: 32-way key merge, flag, worklist; inits rkey ----------
__global__ __launch_bounds__(256) void merge_kernel(
    const unsigned long long* __restrict__ keyc, const unsigned* __restrict__ s2c,
    int* __restrict__ bestIdx, int* __restrict__ flag, int* __restrict__ work,
    int* __restrict__ wcount, unsigned long long* __restrict__ rkey) {
  int t = blockIdx.x * 256 + threadIdx.x;
  if (t >= N_TOK) return;
  rkey[t] = ~0ULL;
  unsigned long long K = ~0ULL; unsigned S = 0xffffffffu;
  for (int c = 0; c < NCHUNK; ++c) {
    unsigned long long k = keyc[(size_t)c * N_TOK + t];
    unsigned s2 = s2c[(size_t)c * N_TOK + t];
    if (k < K) { unsigned o = (unsigned)(K >> 32); S = o < S ? o : S; K = k; }
    else { unsigned o = (unsigned)(k >> 32); S = o < S ? o : S; }
    S = s2 < S ? s2 : S;
  }
  float best_f   = unmapf((unsigned)(K >> 32));
  float second_f = unmapf(S);
  int idx = (int)(unsigned)(K & 0xffffffffu);
  bestIdx[t] = idx;
  bool ok = (second_f - best_f >= CWIN) && (idx >= 0) && (idx < NEMB) && (best_f == best_f);
  flag[t] = ok ? 0 : 1;
  if (!ok) {
    bool nanCase = !(best_f == best_f);
    float limit = best_f + CWIN;
    for (int c = 0; c < NCHUNK; ++c) {
      float cf = unmapf((unsigned)(keyc[(size_t)c * N_TOK + t] >> 32));
      if (nanCase || !(cf > limit)) {               // NaN-safe candidate test
        int pos = atomicAdd(wcount, 1);
        if (pos < WCAP) work[pos] = t * NCHUNK + c;
      }
    }
  }
}

// ---------- kernel 4: f32-emulated rescan, 16 lanes per template ----------
__global__ __launch_bounds__(256) void refine_kernel(
    const float* __restrict__ enc, const float* __restrict__ tmp,
    const float* __restrict__ esq, const float* __restrict__ tsq,
    const int* __restrict__ work, const int* __restrict__ wcount,
    unsigned long long* __restrict__ rkey) {
  int total = *wcount; if (total > WCAP) total = WCAP;
  __shared__ float se[EMB];
  const int wv = threadIdx.x >> 6, lane = threadIdx.x & 63;
  const int g = lane >> 4, l16 = lane & 15;
  for (int p = blockIdx.x; p < total; p += gridDim.x) {
    __syncthreads();
    int item = work[p];
    int token = item / NCHUNK, c = item % NCHUNK;
    const float4* erow = (const float4*)(enc + (size_t)token * EMB);
    for (int i = threadIdx.x; i < 128; i += 256) ((float4*)se)[i] = erow[i];
    __syncthreads();
    float e2 = esq[token];
    unsigned long long lkey = ~0ULL;
#pragma unroll
    for (int j = 0; j < 4; ++j) {
      int m = c * 64 + wv * 16 + j * 4 + g;
      const float4* trow = (const float4*)(tmp + (size_t)m * EMB);
      double s = 0.0;
#pragma unroll
      for (int k = 0; k < 8; ++k) {
        float4 a = trow[l16 + 16 * k];
        float4 b = ((const float4*)se)[l16 + 16 * k];
        s += (double)a.x * b.x + (double)a.y * b.y
           + (double)a.z * b.z + (double)a.w * b.w;
      }
      s += __shfl_xor(s, 1); s += __shfl_xor(s, 2);
      s += __shfl_xor(s, 4); s += __shfl_xor(s, 8);
      if (l16 == 0) {
        float M  = (float)s;
        float d1 = __fadd_rn(e2, -__fmul_rn(2.0f, M));
        float d2 = __fadd_rn(d1, tsq[m]);            // full dist >= 0: bits monotone
        unsigned long long key =
            ((unsigned long long)__float_as_uint(d2) << 32) | (unsigned)m;
        if (key < lkey) lkey = key;
      }
    }
    if (l16 == 0 && lkey != ~0ULL) atomicMin(&rkey[token], lkey);
  }
}

// ---------- kernel 5: gather f32 rows + zidx as f32 ----------
__global__ void gather_kernel(const float* __restrict__ tmp, const int* __restrict__ bestIdx,
                              const int* __restrict__ flag,
                              const unsigned long long* __restrict__ rkey,
                              float* __restrict__ out) {
  int token = blockIdx.x * 4 + (threadIdx.x >> 6);
  int lane = threadIdx.x & 63;
  int idx = flag[token] ? (int)(unsigned)(rkey[token] & 0xffffffffULL) : bestIdx[token];
  idx = idx < 0 ? 0 : (idx > NEMB - 1 ? NEMB - 1 : idx);
  const float4* src = (const float4*)(tmp + (size_t)idx * EMB) + lane * 2;
  float4* dst = (float4*)(out + (size_t)token * EMB) + lane * 2;
  dst[0] = src[0];
  dst[1] = src[1];
  if (lane == 0) out[(size_t)N_TOK * EMB + token] = (float)idx;
}

extern "C" void kernel_launch(void* const* d_in, const int* in_sizes, int n_in,
                              void* d_out, int out_size, void* d_ws, size_t ws_size,
                              hipStream_t stream) {
  const float* enc = (const float*)d_in[0];
  const float* tmp = (const float*)d_in[1];
  float* out = (float*)d_out;
  char* ws = (char*)d_ws;
  unsigned short* thi = (unsigned short*)ws;                 //  2,097,152 B (panel-major)
  unsigned short* ehi = (unsigned short*)(ws + 2097152);     // 16,777,216 B (panel-major)
  float* tsq      = (float*)(ws + 18874368);                 //      8,192 B
  float* esq      = (float*)(ws + 18882560);                 //     65,536 B
  unsigned long long* keyc = (unsigned long long*)(ws + 18948096); // 4,194,304 B
  unsigned* s2c   = (unsigned*)(ws + 23142400);              //  2,097,152 B
  int*   bestIdx  = (int*)  (ws + 25239552);                 //     65,536 B
  int*   flag     = (int*)  (ws + 25305088);                 //     65,536 B
  unsigned long long* rkey = (unsigned long long*)(ws + 25370624); // 131,072 B
  int*   wcount   = (int*)  (ws + 25501696);                 //         64 B
  int*   work     = (int*)  (ws + 25501760);                 //  2,097,152 B

  prep_kernel  <<<4608,      256, 0, stream>>>(tmp, enc, thi, tsq, ehi, esq, wcount);
  score_kernel <<<1024,      256, 0, stream>>>(ehi, thi, tsq, keyc, s2c);
  merge_kernel <<<N_TOK/256, 256, 0, stream>>>(keyc, s2c, bestIdx, flag, work, wcount, rkey);
  refine_kernel<<<1024,      256, 0, stream>>>(enc, tmp, esq, tsq, work, wcount, rkey);
  gather_kernel<<<N_TOK/4,   256, 0, stream>>>(tmp, bestIdx, flag, rkey, out);
}